// Round 4
// baseline (384.144 us; speedup 1.0000x reference)
//
#include <hip/hip_runtime.h>

#define RTOT 12960      // 4 * 3240 rows
#define PAIRS 3240
#define NB_VAR 81
#define HID 256
#define EPS 1e-5f

#define BM 128
#define BN 64
#define BK 32
#define LDST 40   // LDS row stride in bf16 (80 B): rows r,r+8 alias -> 2-way (free per m136)
#define NBLK 256  // == CU count: 1 block/CU guaranteed co-resident at launch_bounds(256,1)
#define NTHR 256
#define NTILE 408      // 102 row-tiles x 4 col-tiles
#define NTILE_OUT 204  // 102 row-tiles x 2 col-tiles

using bf8   = __attribute__((ext_vector_type(8))) short;
using f32x4 = __attribute__((ext_vector_type(4))) float;

__device__ inline ushort f2bf(float f) {
    union { float f; unsigned u; } c; c.f = f;
    unsigned u = c.u + 0x7fffu + ((c.u >> 16) & 1u);
    return (ushort)(u >> 16);
}
__device__ inline unsigned pk2(float a, float b) {
    return (unsigned)f2bf(a) | ((unsigned)f2bf(b) << 16);
}

struct SMem {
    ushort sA[BM * LDST];          // 10240 B
    ushort sB[BN * LDST];          // 5120 B
    float  sS[HID], sT[HID];       // 2048 B
    float  sCS[2][BN], sCQ[2][BN]; // 1024 B
    float  feat[32][4];            // 512 B
};

struct KParams {
    const float *x, *w_in, *b_in, *g1, *beta1, *w1, *bias1, *g2, *beta2,
                *w2, *bias2, *fg, *fbeta, *w_out, *b_out;
    float *out;
    float *buf0, *buf1, *buf2, *stats;
    int2  *pairs;
    ushort *wbf;   // [w1_0 | w1_1 | w2_0 | w2_1 | w_out] each 65536 elems
    int   *bar;    // {count, generation} zeroed by hipMemsetAsync each launch
};

// ---- hand-rolled grid barrier: sense-reversing, agent(device)-scope ----
__device__ __forceinline__ void gbar(int* bar) {
    __syncthreads();
    if (threadIdx.x == 0) {
        __threadfence();   // release my block's global writes (L2 writeback, device scope)
        int gen = __hip_atomic_load(&bar[1], __ATOMIC_RELAXED, __HIP_MEMORY_SCOPE_AGENT);
        int prev = __hip_atomic_fetch_add(&bar[0], 1, __ATOMIC_ACQ_REL, __HIP_MEMORY_SCOPE_AGENT);
        if (prev == NBLK - 1) {
            __hip_atomic_store(&bar[0], 0, __ATOMIC_RELAXED, __HIP_MEMORY_SCOPE_AGENT);
            __hip_atomic_fetch_add(&bar[1], 1, __ATOMIC_RELEASE, __HIP_MEMORY_SCOPE_AGENT);
        } else {
            while (__hip_atomic_load(&bar[1], __ATOMIC_RELAXED, __HIP_MEMORY_SCOPE_AGENT) == gen)
                __builtin_amdgcn_s_sleep(2);
        }
        __threadfence();   // acquire other blocks' writes (cache invalidate)
    }
    __syncthreads();
}

// ---------------- GEMM phase: Y = relu(bn(X)) @ W^T + bias (+res), col stats ----------------
__device__ __forceinline__ void d_gemm(
        const float* __restrict__ X, const float* __restrict__ stin,
        const float* __restrict__ g, const float* __restrict__ beta,
        const ushort* __restrict__ Wb, const float* __restrict__ bias,
        const float* __restrict__ res, float* __restrict__ Y,
        float* __restrict__ stout, SMem& sm, int tile) {
    int tid = threadIdx.x;
    {
        float sum = stin[tid], sq = stin[HID + tid];
        float m = sum * (1.f / RTOT);
        float v = sq * (1.f / RTOT) - m * m;
        float sc = g[tid] * rsqrtf(v + EPS);
        sm.sS[tid] = sc;
        sm.sT[tid] = fmaf(-m, sc, beta[tid]);
    }
    __syncthreads();

    int bm0 = (tile >> 2) * BM;
    int bn0 = (tile & 3) * BN;
    int lane = tid & 63, wid = tid >> 6;
    int wr = wid >> 1, wc = wid & 1;

    f32x4 acc[4][2] = {};

    for (int k0 = 0; k0 < HID; k0 += BK) {
#pragma unroll
        for (int l = 0; l < 4; l++) {
            int lin = tid + l * 256;
            int row = lin >> 3, kv = lin & 7;
            int gr = bm0 + row; gr = gr < RTOT ? gr : RTOT - 1;
            int k = k0 + kv * 4;
            float4 a = *(const float4*)(X + (size_t)gr * HID + k);
            a.x = fmaxf(fmaf(a.x, sm.sS[k + 0], sm.sT[k + 0]), 0.f);
            a.y = fmaxf(fmaf(a.y, sm.sS[k + 1], sm.sT[k + 1]), 0.f);
            a.z = fmaxf(fmaf(a.z, sm.sS[k + 2], sm.sT[k + 2]), 0.f);
            a.w = fmaxf(fmaf(a.w, sm.sS[k + 3], sm.sT[k + 3]), 0.f);
            uint2 pk = make_uint2(pk2(a.x, a.y), pk2(a.z, a.w));
            *(uint2*)&sm.sA[row * LDST + kv * 4] = pk;
        }
        {
            int row = tid >> 2, c = tid & 3;
            uint4 wv = *(const uint4*)(Wb + (size_t)(bn0 + row) * HID + k0 + c * 8);
            *(uint4*)&sm.sB[row * LDST + c * 8] = wv;
        }
        __syncthreads();
        bf8 af[4], bfr[2];
#pragma unroll
        for (int m = 0; m < 4; m++)
            af[m] = *(const bf8*)&sm.sA[(wr * 64 + m * 16 + (lane & 15)) * LDST + (lane >> 4) * 8];
#pragma unroll
        for (int n = 0; n < 2; n++)
            bfr[n] = *(const bf8*)&sm.sB[(wc * 32 + n * 16 + (lane & 15)) * LDST + (lane >> 4) * 8];
#pragma unroll
        for (int m = 0; m < 4; m++)
#pragma unroll
            for (int n = 0; n < 2; n++)
                acc[m][n] = __builtin_amdgcn_mfma_f32_16x16x32_bf16(af[m], bfr[n], acc[m][n], 0, 0, 0);
        __syncthreads();
    }

    int rb = bm0 + wr * 64;
    int cb = bn0 + wc * 32;
    float csum[2] = {0.f, 0.f}, csq[2] = {0.f, 0.f};
#pragma unroll
    for (int n = 0; n < 2; n++) {
        int col = cb + n * 16 + (lane & 15);
        float bv = bias[col];
#pragma unroll
        for (int m = 0; m < 4; m++) {
#pragma unroll
            for (int i = 0; i < 4; i++) {
                int r = rb + m * 16 + (lane >> 4) * 4 + i;
                if (r < RTOT) {
                    float v = acc[m][n][i] + bv;
                    if (res) v += res[(size_t)r * HID + col];
                    Y[(size_t)r * HID + col] = v;
                    csum[n] += v; csq[n] += v * v;
                }
            }
        }
    }
#pragma unroll
    for (int n = 0; n < 2; n++) {
        float s = csum[n], q = csq[n];
        s += __shfl_xor(s, 16); q += __shfl_xor(q, 16);
        s += __shfl_xor(s, 32); q += __shfl_xor(q, 32);
        if (lane < 16) {
            int lc = wc * 32 + n * 16 + lane;
            sm.sCS[wr][lc] = s; sm.sCQ[wr][lc] = q;
        }
    }
    __syncthreads();
    if (tid < 2 * BN) {
        int col = tid & (BN - 1), q = tid >> 6;
        float v = q ? (sm.sCQ[0][col] + sm.sCQ[1][col]) : (sm.sCS[0][col] + sm.sCS[1][col]);
        atomicAdd(&stout[q * HID + bn0 + col], v);
    }
    __syncthreads();
}

// ---------------- final GEMM (N=81) with fused symmetric scatter ----------------
__device__ __forceinline__ void d_gout(
        const float* __restrict__ X, const float* __restrict__ stin,
        const float* __restrict__ g, const float* __restrict__ beta,
        const ushort* __restrict__ Wb, const float* __restrict__ b_out,
        const int2* __restrict__ pairs, float* __restrict__ out,
        SMem& sm, int tile) {
    int tid = threadIdx.x;
    {
        float sum = stin[tid], sq = stin[HID + tid];
        float m = sum * (1.f / RTOT);
        float v = sq * (1.f / RTOT) - m * m;
        float sc = g[tid] * rsqrtf(v + EPS);
        sm.sS[tid] = sc;
        sm.sT[tid] = fmaf(-m, sc, beta[tid]);
    }
    __syncthreads();

    int bm0 = (tile >> 1) * BM;
    int bn0 = (tile & 1) * BN;
    int lane = tid & 63, wid = tid >> 6;
    int wr = wid >> 1, wc = wid & 1;

    f32x4 acc[4][2] = {};

    for (int k0 = 0; k0 < HID; k0 += BK) {
#pragma unroll
        for (int l = 0; l < 4; l++) {
            int lin = tid + l * 256;
            int row = lin >> 3, kv = lin & 7;
            int gr = bm0 + row; gr = gr < RTOT ? gr : RTOT - 1;
            int k = k0 + kv * 4;
            float4 a = *(const float4*)(X + (size_t)gr * HID + k);
            a.x = fmaxf(fmaf(a.x, sm.sS[k + 0], sm.sT[k + 0]), 0.f);
            a.y = fmaxf(fmaf(a.y, sm.sS[k + 1], sm.sT[k + 1]), 0.f);
            a.z = fmaxf(fmaf(a.z, sm.sS[k + 2], sm.sT[k + 2]), 0.f);
            a.w = fmaxf(fmaf(a.w, sm.sS[k + 3], sm.sT[k + 3]), 0.f);
            uint2 pk = make_uint2(pk2(a.x, a.y), pk2(a.z, a.w));
            *(uint2*)&sm.sA[row * LDST + kv * 4] = pk;
        }
        {
            int row = tid >> 2, c = tid & 3;
            int gn = bn0 + row; gn = gn < 81 ? gn : 80;
            uint4 wv = *(const uint4*)(Wb + (size_t)gn * HID + k0 + c * 8);
            *(uint4*)&sm.sB[row * LDST + c * 8] = wv;
        }
        __syncthreads();
        bf8 af[4], bfr[2];
#pragma unroll
        for (int m = 0; m < 4; m++)
            af[m] = *(const bf8*)&sm.sA[(wr * 64 + m * 16 + (lane & 15)) * LDST + (lane >> 4) * 8];
#pragma unroll
        for (int n = 0; n < 2; n++)
            bfr[n] = *(const bf8*)&sm.sB[(wc * 32 + n * 16 + (lane & 15)) * LDST + (lane >> 4) * 8];
#pragma unroll
        for (int m = 0; m < 4; m++)
#pragma unroll
            for (int n = 0; n < 2; n++)
                acc[m][n] = __builtin_amdgcn_mfma_f32_16x16x32_bf16(af[m], bfr[n], acc[m][n], 0, 0, 0);
        __syncthreads();
    }

    int rb = bm0 + wr * 64;
    int cb = bn0 + wc * 32;
    int tcol[2], ttr[2]; float bv[2]; bool tok[2];
#pragma unroll
    for (int n = 0; n < 2; n++) {
        int t = cb + n * 16 + (lane & 15);
        tok[n] = t < 81;
        int tc = tok[n] ? t : 0;
        tcol[n] = tc;
        int gi = tc / 9, gj = tc - gi * 9;
        ttr[n] = gj * 9 + gi;
        bv[n] = b_out[tc];
    }
#pragma unroll
    for (int m = 0; m < 4; m++) {
#pragma unroll
        for (int i = 0; i < 4; i++) {
            int r = rb + m * 16 + (lane >> 4) * 4 + i;
            if (r >= RTOT) continue;
            int b = r / PAIRS, p = r - b * PAIRS;
            int2 ij = pairs[p];
            size_t base1 = ((size_t)(b * NB_VAR + ij.x) * NB_VAR + ij.y) * 81;
            size_t base2 = ((size_t)(b * NB_VAR + ij.y) * NB_VAR + ij.x) * 81;
#pragma unroll
            for (int n = 0; n < 2; n++) {
                if (!tok[n]) continue;
                float v = acc[m][n][i] + bv[n];
                out[base1 + tcol[n]] = v;
                out[base2 + ttr[n]] = v;
            }
        }
    }
    __syncthreads();
}

// ---------------- the fused persistent kernel ----------------
__global__ __launch_bounds__(NTHR, 1) void fused(KParams p) {
    __shared__ SMem sm;
    int tid = threadIdx.x;
    int b = blockIdx.x;
    int gtid = b * NTHR + tid;

    // ---- phase 0: weight conversion, pairs, zero stats, zero out-diagonal ----
    for (int i = gtid; i < 262144 + 81 * 256; i += NBLK * NTHR) {
        float v;
        if (i < 131072)      v = p.w1[i];
        else if (i < 262144) v = p.w2[i - 131072];
        else                 v = p.w_out[i - 262144];
        p.wbf[i] = f2bf(v);
    }
    if (gtid < 5 * 512) p.stats[gtid] = 0.f;
    if (gtid < PAIRS) {
        int q = gtid, i = 0, off = 0;
        while (off + (NB_VAR - 1 - i) <= q) { off += NB_VAR - 1 - i; i++; }
        p.pairs[gtid] = make_int2(i, i + 1 + (q - off));
    }
    if (gtid < 4 * NB_VAR * 81) {
        int bb = gtid / (NB_VAR * 81);
        int rem = gtid - bb * (NB_VAR * 81);
        int i = rem / 81, t = rem - i * 81;
        p.out[((size_t)(bb * NB_VAR + i) * NB_VAR + i) * 81 + t] = 0.f;
    }
    gbar(p.bar);

    // ---- phase 1: input projection + stats0 (405 groups of 32 rows) ----
    {
        float4 w = ((const float4*)p.w_in)[tid];
        float bi = p.b_in[tid];
        float s = 0.f, s2 = 0.f;
        for (int grp = b; grp < 405; grp += NBLK) {
            int r0 = grp * 32;
            __syncthreads();
            if (tid < 32) {
                int r = r0 + tid;
                int bb = r / PAIRS, pp = r - bb * PAIRS;
                int2 ij = p.pairs[pp];
                const float* xb = p.x + bb * NB_VAR * 2;
                sm.feat[tid][0] = xb[ij.x * 2 + 0];
                sm.feat[tid][1] = xb[ij.x * 2 + 1];
                sm.feat[tid][2] = xb[ij.y * 2 + 0];
                sm.feat[tid][3] = xb[ij.y * 2 + 1];
            }
            __syncthreads();
            for (int t = 0; t < 32; t++) {
                float v = fmaf(sm.feat[t][0], w.x, fmaf(sm.feat[t][1], w.y,
                          fmaf(sm.feat[t][2], w.z, fmaf(sm.feat[t][3], w.w, bi))));
                v = fmaxf(v, 0.f);
                p.buf0[(size_t)(r0 + t) * HID + tid] = v;
                s += v; s2 += v * v;
            }
        }
        atomicAdd(&p.stats[tid], s);
        atomicAdd(&p.stats[HID + tid], s2);
    }
    gbar(p.bar);

    // ---- phases 2-5: the four 256x256 GEMMs (408 tiles, grid-strided) ----
    for (int t = b; t < NTILE; t += NBLK)
        d_gemm(p.buf0, p.stats + 0 * 512, p.g1, p.beta1,
               p.wbf + 0 * 65536, p.bias1, nullptr, p.buf1, p.stats + 1 * 512, sm, t);
    gbar(p.bar);
    for (int t = b; t < NTILE; t += NBLK)
        d_gemm(p.buf1, p.stats + 1 * 512, p.g2, p.beta2,
               p.wbf + 2 * 65536, p.bias2, p.buf0, p.buf2, p.stats + 2 * 512, sm, t);
    gbar(p.bar);
    for (int t = b; t < NTILE; t += NBLK)
        d_gemm(p.buf2, p.stats + 2 * 512, p.g1 + HID, p.beta1 + HID,
               p.wbf + 1 * 65536, p.bias1 + HID, nullptr, p.buf1, p.stats + 3 * 512, sm, t);
    gbar(p.bar);
    for (int t = b; t < NTILE; t += NBLK)
        d_gemm(p.buf1, p.stats + 3 * 512, p.g2 + HID, p.beta2 + HID,
               p.wbf + 3 * 65536, p.bias2 + HID, p.buf2, p.buf0, p.stats + 4 * 512, sm, t);
    gbar(p.bar);

    // ---- phase 6: output GEMM + symmetric scatter (204 tiles) ----
    for (int t = b; t < NTILE_OUT; t += NBLK)
        d_gout(p.buf0, p.stats + 4 * 512, p.fg, p.fbeta,
               p.wbf + 4 * 65536, p.b_out, p.pairs, p.out, sm, t);
}

extern "C" void kernel_launch(void* const* d_in, const int* in_sizes, int n_in,
                              void* d_out, int out_size, void* d_ws, size_t ws_size,
                              hipStream_t stream) {
    KParams p;
    p.x     = (const float*)d_in[0];
    p.w_in  = (const float*)d_in[1];
    p.b_in  = (const float*)d_in[2];
    p.g1    = (const float*)d_in[3];
    p.beta1 = (const float*)d_in[4];
    p.w1    = (const float*)d_in[5];
    p.bias1 = (const float*)d_in[6];
    p.g2    = (const float*)d_in[7];
    p.beta2 = (const float*)d_in[8];
    p.w2    = (const float*)d_in[9];
    p.bias2 = (const float*)d_in[10];
    p.fg    = (const float*)d_in[11];
    p.fbeta = (const float*)d_in[12];
    p.w_out = (const float*)d_in[13];
    p.b_out = (const float*)d_in[14];
    p.out   = (float*)d_out;

    p.buf0  = (float*)d_ws;
    p.buf1  = p.buf0 + (size_t)RTOT * HID;
    p.buf2  = p.buf1 + (size_t)RTOT * HID;
    float* stats = p.buf2 + (size_t)RTOT * HID;
    p.stats = stats;
    p.pairs = (int2*)(stats + 5 * 512);
    p.wbf   = (ushort*)(p.pairs + PAIRS);
    p.bar   = (int*)(p.wbf + 5 * 65536);

    hipMemsetAsync(p.bar, 0, 2 * sizeof(int), stream);
    fused<<<NBLK, NTHR, 0, stream>>>(p);
}

// Round 5
// 111.219 us; speedup vs baseline: 3.4539x; 3.4539x over previous
//
#include <hip/hip_runtime.h>

#define RTOT 12960      // 4 * 3240 rows
#define PAIRS 3240
#define NB_VAR 81
#define HID 256
#define EPS 1e-5f

#define BM 64
#define BN 64
#define BK 32
#define LDST 40   // LDS row stride in bf16 (80 B): rows r,r+8 alias -> 2-way (free per m136)
#define NRT 203   // ceil(12960/64) row tiles

using bf8   = __attribute__((ext_vector_type(8))) short;
using f32x4 = __attribute__((ext_vector_type(4))) float;

__device__ inline ushort f2bf(float f) {
    union { float f; unsigned u; } c; c.f = f;
    unsigned u = c.u + 0x7fffu + ((c.u >> 16) & 1u);
    return (ushort)(u >> 16);
}
__device__ inline float bf2f(ushort h) {
    union { unsigned u; float f; } c; c.u = (unsigned)h << 16;
    return c.f;
}
__device__ inline unsigned pk2(float a, float b) {
    return (unsigned)f2bf(a) | ((unsigned)f2bf(b) << 16);
}

// ---------------- prep: weights->bf16, pairs, zero stats, zero out-diagonal ----------------
__global__ void k_prep(const float* __restrict__ w1, const float* __restrict__ w2,
                       const float* __restrict__ w_out, ushort* __restrict__ wbf,
                       int2* __restrict__ pairs, float* __restrict__ stats,
                       float* __restrict__ out) {
    int idx = blockIdx.x * blockDim.x + threadIdx.x;
    if (idx < 262144 + 81 * 256) {
        float v;
        if (idx < 131072)      v = w1[idx];
        else if (idx < 262144) v = w2[idx - 131072];
        else                   v = w_out[idx - 262144];
        wbf[idx] = f2bf(v);
    }
    if (idx < 5 * 512) stats[idx] = 0.f;
    if (idx < PAIRS) {
        int q = idx, i = 0, off = 0;
        while (off + (NB_VAR - 1 - i) <= q) { off += NB_VAR - 1 - i; i++; }
        pairs[idx] = make_int2(i, i + 1 + (q - off));
    }
    if (idx < 4 * NB_VAR * 81) {
        int b = idx / (NB_VAR * 81);
        int rem = idx - b * (NB_VAR * 81);
        int i = rem / 81, t = rem - i * 81;
        out[((size_t)(b * NB_VAR + i) * NB_VAR + i) * 81 + t] = 0.f;
    }
}

// ---------------- input projection + stats0; h0 stored bf16 ----------------
__global__ __launch_bounds__(256) void k_in(
        const float* __restrict__ x, const float* __restrict__ w_in,
        const float* __restrict__ b_in, const int2* __restrict__ pairs,
        ushort* __restrict__ h0, float* __restrict__ st) {
    __shared__ float feat[32][4];
    int tid = threadIdx.x;
    int r0 = blockIdx.x * 32;
    if (tid < 32) {
        int r = r0 + tid;
        int b = r / PAIRS, p = r - b * PAIRS;
        int2 ij = pairs[p];
        const float* xb = x + b * NB_VAR * 2;
        feat[tid][0] = xb[ij.x * 2 + 0];
        feat[tid][1] = xb[ij.x * 2 + 1];
        feat[tid][2] = xb[ij.y * 2 + 0];
        feat[tid][3] = xb[ij.y * 2 + 1];
    }
    __syncthreads();
    float4 w = ((const float4*)w_in)[tid];
    float bi = b_in[tid];
    float s = 0.f, s2 = 0.f;
    for (int t = 0; t < 32; t++) {
        float v = fmaf(feat[t][0], w.x, fmaf(feat[t][1], w.y,
                  fmaf(feat[t][2], w.z, fmaf(feat[t][3], w.w, bi))));
        v = fmaxf(v, 0.f);
        h0[(size_t)(r0 + t) * HID + tid] = f2bf(v);
        s += v; s2 += v * v;
    }
    atomicAdd(&st[tid], s);
    atomicAdd(&st[HID + tid], s2);
}

// ---------------- MFMA GEMM: Y = relu(bn(X)) @ W^T + bias (+res), col stats ----------------
// X: RTOT x 256 bf16 (raw). Wb: 256 x 256 bf16. Y: RTOT x 256 bf16.
__global__ __launch_bounds__(256) void k_gemm(
        const ushort* __restrict__ X, const float* __restrict__ stin,
        const float* __restrict__ g, const float* __restrict__ beta,
        const ushort* __restrict__ Wb, const float* __restrict__ bias,
        const ushort* __restrict__ res, ushort* __restrict__ Y,
        float* __restrict__ stout) {
    __shared__ ushort sA[BM * LDST];
    __shared__ ushort sB[BN * LDST];
    __shared__ float sS[HID], sT[HID];
    __shared__ float sCS[2][BN], sCQ[2][BN];

    int tid = threadIdx.x;
    {
        float sum = stin[tid], sq = stin[HID + tid];
        float m = sum * (1.f / RTOT);
        float v = sq * (1.f / RTOT) - m * m;
        float sc = g[tid] * rsqrtf(v + EPS);
        sS[tid] = sc;
        sT[tid] = fmaf(-m, sc, beta[tid]);
    }
    __syncthreads();

    int bm0 = blockIdx.x * BM;
    int bn0 = blockIdx.y * BN;
    int lane = tid & 63, wid = tid >> 6;
    int wr = wid >> 1, wc = wid & 1;

    f32x4 acc[2][2] = {};

    int arow = tid >> 2, akq = tid & 3;          // A/B staging: 1x 16B per thread
    int gra = bm0 + arow; gra = gra < RTOT ? gra : RTOT - 1;

    for (int k0 = 0; k0 < HID; k0 += BK) {
        {
            int k = k0 + akq * 8;
            ushort4 xv4[2];
            *(uint4*)xv4 = *(const uint4*)(X + (size_t)gra * HID + k);
            const ushort* xv = (const ushort*)xv4;
            unsigned pk[4];
#pragma unroll
            for (int e = 0; e < 4; e++) {
                float a0 = fmaxf(fmaf(bf2f(xv[2*e+0]), sS[k + 2*e+0], sT[k + 2*e+0]), 0.f);
                float a1 = fmaxf(fmaf(bf2f(xv[2*e+1]), sS[k + 2*e+1], sT[k + 2*e+1]), 0.f);
                pk[e] = pk2(a0, a1);
            }
            *(uint4*)&sA[arow * LDST + akq * 8] = *(uint4*)pk;
            uint4 wv = *(const uint4*)(Wb + (size_t)(bn0 + arow) * HID + k);
            *(uint4*)&sB[arow * LDST + akq * 8] = wv;
        }
        __syncthreads();
        bf8 af[2], bfr[2];
#pragma unroll
        for (int m = 0; m < 2; m++)
            af[m] = *(const bf8*)&sA[(wr * 32 + m * 16 + (lane & 15)) * LDST + (lane >> 4) * 8];
#pragma unroll
        for (int n = 0; n < 2; n++)
            bfr[n] = *(const bf8*)&sB[(wc * 32 + n * 16 + (lane & 15)) * LDST + (lane >> 4) * 8];
#pragma unroll
        for (int m = 0; m < 2; m++)
#pragma unroll
            for (int n = 0; n < 2; n++)
                acc[m][n] = __builtin_amdgcn_mfma_f32_16x16x32_bf16(af[m], bfr[n], acc[m][n], 0, 0, 0);
        __syncthreads();
    }

    int rb = bm0 + wr * 32;
    int cb = bn0 + wc * 32;
    float csum[2] = {0.f, 0.f}, csq[2] = {0.f, 0.f};
#pragma unroll
    for (int n = 0; n < 2; n++) {
        int col = cb + n * 16 + (lane & 15);
        float bv = bias[col];
#pragma unroll
        for (int m = 0; m < 2; m++) {
#pragma unroll
            for (int i = 0; i < 4; i++) {
                int r = rb + m * 16 + (lane >> 4) * 4 + i;
                if (r < RTOT) {
                    float v = acc[m][n][i] + bv;
                    if (res) v += bf2f(res[(size_t)r * HID + col]);
                    Y[(size_t)r * HID + col] = f2bf(v);
                    csum[n] += v; csq[n] += v * v;
                }
            }
        }
    }
#pragma unroll
    for (int n = 0; n < 2; n++) {
        float s = csum[n], q = csq[n];
        s += __shfl_xor(s, 16); q += __shfl_xor(q, 16);
        s += __shfl_xor(s, 32); q += __shfl_xor(q, 32);
        if (lane < 16) {
            int lc = wc * 32 + n * 16 + lane;
            sCS[wr][lc] = s; sCQ[wr][lc] = q;
        }
    }
    __syncthreads();
    if (tid < 2 * BN) {
        int col = tid & (BN - 1), q = tid >> 6;
        float v = q ? (sCQ[0][col] + sCQ[1][col]) : (sCS[0][col] + sCS[1][col]);
        atomicAdd(&stout[q * HID + bn0 + col], v);
    }
}

// ---------------- final GEMM (N=81) with fused symmetric scatter ----------------
__global__ __launch_bounds__(256) void k_gout(
        const ushort* __restrict__ X, const float* __restrict__ stin,
        const float* __restrict__ g, const float* __restrict__ beta,
        const ushort* __restrict__ Wb, const float* __restrict__ b_out,
        const int2* __restrict__ pairs, float* __restrict__ out) {
    __shared__ ushort sA[BM * LDST];
    __shared__ ushort sB[BN * LDST];
    __shared__ float sS[HID], sT[HID];

    int tid = threadIdx.x;
    {
        float sum = stin[tid], sq = stin[HID + tid];
        float m = sum * (1.f / RTOT);
        float v = sq * (1.f / RTOT) - m * m;
        float sc = g[tid] * rsqrtf(v + EPS);
        sS[tid] = sc;
        sT[tid] = fmaf(-m, sc, beta[tid]);
    }
    __syncthreads();

    int bm0 = blockIdx.x * BM;
    int bn0 = blockIdx.y * BN;
    int lane = tid & 63, wid = tid >> 6;
    int wr = wid >> 1, wc = wid & 1;

    f32x4 acc[2][2] = {};

    int arow = tid >> 2, akq = tid & 3;
    int gra = bm0 + arow; gra = gra < RTOT ? gra : RTOT - 1;
    int gnb = bn0 + arow; gnb = gnb < 81 ? gnb : 80;

    for (int k0 = 0; k0 < HID; k0 += BK) {
        {
            int k = k0 + akq * 8;
            ushort4 xv4[2];
            *(uint4*)xv4 = *(const uint4*)(X + (size_t)gra * HID + k);
            const ushort* xv = (const ushort*)xv4;
            unsigned pk[4];
#pragma unroll
            for (int e = 0; e < 4; e++) {
                float a0 = fmaxf(fmaf(bf2f(xv[2*e+0]), sS[k + 2*e+0], sT[k + 2*e+0]), 0.f);
                float a1 = fmaxf(fmaf(bf2f(xv[2*e+1]), sS[k + 2*e+1], sT[k + 2*e+1]), 0.f);
                pk[e] = pk2(a0, a1);
            }
            *(uint4*)&sA[arow * LDST + akq * 8] = *(uint4*)pk;
            uint4 wv = *(const uint4*)(Wb + (size_t)gnb * HID + k);
            *(uint4*)&sB[arow * LDST + akq * 8] = wv;
        }
        __syncthreads();
        bf8 af[2], bfr[2];
#pragma unroll
        for (int m = 0; m < 2; m++)
            af[m] = *(const bf8*)&sA[(wr * 32 + m * 16 + (lane & 15)) * LDST + (lane >> 4) * 8];
#pragma unroll
        for (int n = 0; n < 2; n++)
            bfr[n] = *(const bf8*)&sB[(wc * 32 + n * 16 + (lane & 15)) * LDST + (lane >> 4) * 8];
#pragma unroll
        for (int m = 0; m < 2; m++)
#pragma unroll
            for (int n = 0; n < 2; n++)
                acc[m][n] = __builtin_amdgcn_mfma_f32_16x16x32_bf16(af[m], bfr[n], acc[m][n], 0, 0, 0);
        __syncthreads();
    }

    int rb = bm0 + wr * 32;
    int cb = bn0 + wc * 32;
    int tcol[2], ttr[2]; float bv[2]; bool tok[2];
#pragma unroll
    for (int n = 0; n < 2; n++) {
        int t = cb + n * 16 + (lane & 15);
        tok[n] = t < 81;
        int tc = tok[n] ? t : 0;
        tcol[n] = tc;
        int gi = tc / 9, gj = tc - gi * 9;
        ttr[n] = gj * 9 + gi;
        bv[n] = b_out[tc];
    }
#pragma unroll
    for (int m = 0; m < 2; m++) {
#pragma unroll
        for (int i = 0; i < 4; i++) {
            int r = rb + m * 16 + (lane >> 4) * 4 + i;
            if (r >= RTOT) continue;
            int b = r / PAIRS, p = r - b * PAIRS;
            int2 ij = pairs[p];
            size_t base1 = ((size_t)(b * NB_VAR + ij.x) * NB_VAR + ij.y) * 81;
            size_t base2 = ((size_t)(b * NB_VAR + ij.y) * NB_VAR + ij.x) * 81;
#pragma unroll
            for (int n = 0; n < 2; n++) {
                if (!tok[n]) continue;
                float v = acc[m][n][i] + bv[n];
                out[base1 + tcol[n]] = v;
                out[base2 + ttr[n]] = v;
            }
        }
    }
}

extern "C" void kernel_launch(void* const* d_in, const int* in_sizes, int n_in,
                              void* d_out, int out_size, void* d_ws, size_t ws_size,
                              hipStream_t stream) {
    const float* x     = (const float*)d_in[0];
    const float* w_in  = (const float*)d_in[1];
    const float* b_in  = (const float*)d_in[2];
    const float* g1    = (const float*)d_in[3];
    const float* beta1 = (const float*)d_in[4];
    const float* w1    = (const float*)d_in[5];
    const float* bias1 = (const float*)d_in[6];
    const float* g2    = (const float*)d_in[7];
    const float* beta2 = (const float*)d_in[8];
    const float* w2    = (const float*)d_in[9];
    const float* bias2 = (const float*)d_in[10];
    const float* fg    = (const float*)d_in[11];
    const float* fbeta = (const float*)d_in[12];
    const float* w_out = (const float*)d_in[13];
    const float* b_out = (const float*)d_in[14];
    float* out = (float*)d_out;

    ushort* buf0 = (ushort*)d_ws;
    ushort* buf1 = buf0 + (size_t)RTOT * HID;
    ushort* buf2 = buf1 + (size_t)RTOT * HID;
    ushort* wbf  = buf2 + (size_t)RTOT * HID;   // 5*65536 elems
    float* stats = (float*)(wbf + 5 * 65536);
    int2*  pairs = (int2*)(stats + 5 * 512);
    // wbf layout: w1_0 @0, w1_1 @65536, w2_0 @131072, w2_1 @196608, w_out @262144

    k_prep<<<1105, 256, 0, stream>>>(w1, w2, w_out, wbf, pairs, stats, out);
    k_in<<<405, 256, 0, stream>>>(x, w_in, b_in, pairs, buf0, stats + 0 * 512);

    dim3 gmid(NRT, HID / BN);   // (203, 4)
    dim3 gfin(NRT, 2);          // (203, 2): cols 0-63 / 64-80

    k_gemm<<<gmid, 256, 0, stream>>>(buf0, stats + 0 * 512, g1, beta1,
                                     wbf + 0 * 65536, bias1, nullptr, buf1, stats + 1 * 512);
    k_gemm<<<gmid, 256, 0, stream>>>(buf1, stats + 1 * 512, g2, beta2,
                                     wbf + 2 * 65536, bias2, buf0, buf2, stats + 2 * 512);
    k_gemm<<<gmid, 256, 0, stream>>>(buf2, stats + 2 * 512, g1 + HID, beta1 + HID,
                                     wbf + 1 * 65536, bias1 + HID, nullptr, buf1, stats + 3 * 512);
    k_gemm<<<gmid, 256, 0, stream>>>(buf1, stats + 3 * 512, g2 + HID, beta2 + HID,
                                     wbf + 3 * 65536, bias2 + HID, buf2, buf0, stats + 4 * 512);
    k_gout<<<gfin, 256, 0, stream>>>(buf0, stats + 4 * 512, fg, fbeta,
                                     wbf + 4 * 65536, b_out, pairs, out);
}